// Round 9
// baseline (672.656 us; speedup 1.0000x reference)
//
#include <hip/hip_runtime.h>

// Problem constants
#define NN   102400      // nodes
#define NE   3276800     // edges
#define TT   64          // in channels
#define HH   32          // hidden
#define BSC  16          // conv3 out channels
#define NG   256         // graphs
#define NC   9           // classes
#define F1   256         // fc1 out
#define F2   128         // fc2 out
#define FIN  6400        // 400*16, fc1 in

#define NBUCK 200        // NN / 512 buckets (by node>>9)
#define CAP   18432      // slots per bucket region (mean 16384, +16 sigma)
#define TILE  8192       // edges per partition workgroup (NE/TILE = 400 wgs)

// ---------------- bucket cursor init ----------------

__global__ __launch_bounds__(256) void k_init(int* __restrict__ scur,
                                              int* __restrict__ dcur) {
    int t = threadIdx.x;
    if (t < NBUCK) { scur[t] = t * CAP; dcur[t] = t * CAP; }
}

// ---------------- LDS-staged partition by (src|dst)>>9 ----------------
// MODE 0: bucket by src, payload {src&511, ew}
// MODE 1: bucket by dst, payload {(src<<9)|(dst&511), ew}
template<int MODE>
__global__ __launch_bounds__(256) void k_part(const int* __restrict__ src,
                                              const int* __restrict__ dst,
                                              const float* __restrict__ ew,
                                              int* __restrict__ gcur,
                                              int2* __restrict__ outbuf) {
    __shared__ int hist[256];
    __shared__ int base[256];
    __shared__ int cur[256];
    __shared__ int gpos[256];
    __shared__ int2 stage[TILE];
    __shared__ unsigned char bkt[TILE];

    int t = threadIdx.x;
    int e0 = blockIdx.x * TILE;

    hist[t] = 0;
    __syncthreads();
    // phase 1: tile histogram
#pragma unroll
    for (int i = 0; i < TILE / 256; ++i) {
        int e = e0 + i * 256 + t;
        int key = MODE ? dst[e] : src[e];
        atomicAdd(&hist[key >> 9], 1);
    }
    __syncthreads();
    // phase 2: exclusive scan -> base
    int h = hist[t];
    base[t] = h;
    __syncthreads();
    for (int off = 1; off < 256; off <<= 1) {
        int add = (t >= off) ? base[t - off] : 0;
        __syncthreads();
        base[t] += add;
        __syncthreads();
    }
    int excl = base[t] - h;
    __syncthreads();
    base[t] = excl;
    cur[t] = excl;
    __syncthreads();
    // phase 3: place into LDS
#pragma unroll
    for (int i = 0; i < TILE / 256; ++i) {
        int e = e0 + i * 256 + t;
        int s = src[e];
        int w = __float_as_int(ew[e]);
        int key, pack;
        if (MODE) { int d = dst[e]; key = d; pack = (s << 9) | (d & 511); }
        else      { key = s; pack = s & 511; }
        int b = key >> 9;
        int p = atomicAdd(&cur[b], 1);
        stage[p] = make_int2(pack, w);
        bkt[p] = (unsigned char)b;
    }
    __syncthreads();
    // phase 4: claim contiguous global ranges in this bucket's region
    if (t < NBUCK && h > 0) gpos[t] = atomicAdd(&gcur[t], h);
    __syncthreads();
    // phase 5: coalesced flush
#pragma unroll
    for (int i = 0; i < TILE / 256; ++i) {
        int p = i * 256 + t;
        int b = bkt[p];
        outbuf[gpos[b] + (p - base[b])] = stage[p];
    }
}

// ---------------- per-src-bucket weighted degree -> dinv (LDS histogram) ---

__global__ __launch_bounds__(512) void k_deg2(const int* __restrict__ scur,
                                              const int2* __restrict__ sbuck,
                                              float* __restrict__ dinv) {
    __shared__ float acc[512];
    int b = blockIdx.x, t = threadIdx.x;
    acc[t] = 0.f;
    __syncthreads();
    int lo = b * CAP, hi = scur[b];
    for (int j = lo + t; j < hi; j += 512) {
        int2 e = sbuck[j];
        atomicAdd(&acc[e.x], __int_as_float(e.y));
    }
    __syncthreads();
    float v = acc[t];
    dinv[b * 512 + t] = v > 0.f ? rsqrtf(v) : 0.f;
}

// ---------------- per-dst-bucket CSR finalize (LDS hist+scan+cursors) ------
// edata[slot] = {src, lapw}; rowbeg/rowend delimit each node's edges.

__global__ __launch_bounds__(512) void k_fin(const int* __restrict__ dcur,
                                             const int2* __restrict__ dbuck,
                                             const float* __restrict__ dinv,
                                             int2* __restrict__ edata,
                                             int* __restrict__ rowbeg,
                                             int* __restrict__ rowend) {
    __shared__ float dl[512];
    __shared__ int cnt[512];
    __shared__ int base[512];
    __shared__ int cur[512];
    int b = blockIdx.x, t = threadIdx.x;
    dl[t] = dinv[b * 512 + t];
    cnt[t] = 0;
    __syncthreads();
    int lo = b * CAP, hi = dcur[b];
    for (int j = lo + t; j < hi; j += 512)
        atomicAdd(&cnt[dbuck[j].x & 511], 1);
    __syncthreads();
    int h = cnt[t];
    base[t] = h;
    __syncthreads();
    for (int off = 1; off < 512; off <<= 1) {
        int add = (t >= off) ? base[t - off] : 0;
        __syncthreads();
        base[t] += add;
        __syncthreads();
    }
    int beg = lo + base[t] - h;
    rowbeg[b * 512 + t] = beg;
    rowend[b * 512 + t] = beg + h;
    cur[t] = beg;
    __syncthreads();
    for (int j = lo + t; j < hi; j += 512) {
        int2 e = dbuck[j];
        int dlow = e.x & 511;
        int s = e.x >> 9;
        float lw = -dinv[s] * __int_as_float(e.y) * dl[dlow];
        int slot = atomicAdd(&cur[dlow], 1);
        edata[slot] = make_int2(s, __float_as_int(lw));
    }
}

// ---------------- per-node dual GEMM (h@W0 and h@W1) ----------------
template<int CIN, int COUT>
__global__ __launch_bounds__(256) void k_dual_gemm(const float* __restrict__ in,
                                                   const float* __restrict__ W0,
                                                   const float* __restrict__ W1,
                                                   float* __restrict__ o0,
                                                   float* __restrict__ o1) {
    int node = blockIdx.x * 256 + threadIdx.x;
    const float* row = in + (size_t)node * CIN;
    float a0[COUT], a1[COUT];
#pragma unroll
    for (int c = 0; c < COUT; ++c) { a0[c] = 0.f; a1[c] = 0.f; }
    for (int k = 0; k < CIN; ++k) {
        float xv = row[k];
#pragma unroll
        for (int c = 0; c < COUT; ++c) {
            a0[c] = fmaf(xv, W0[k * COUT + c], a0[c]);
            a1[c] = fmaf(xv, W1[k * COUT + c], a1[c]);
        }
    }
#pragma unroll
    for (int c = 0; c < COUT; ++c) {
        o0[(size_t)node * COUT + c] = a0[c];
        o1[(size_t)node * COUT + c] = a1[c];
    }
}

// ---------------- CSR gather fused with bias+relu --------------------------
// out[n,c] = relu(a[n,c] + sum_e lapw_e * xw[src_e, c] + bias[c])
// float2 per lane (C/2 lanes per edge), 16-deep branch-free load pipeline.
template<int C>
__global__ __launch_bounds__(256) void k_gather(const int* __restrict__ rowbeg,
                                                const int* __restrict__ rowend,
                                                const int2* __restrict__ edata,
                                                const float* __restrict__ xw,
                                                const float* __restrict__ a,
                                                const float* __restrict__ bias,
                                                float* __restrict__ out) {
    constexpr int L = C / 2;          // lanes per edge (float2 each)
    constexpr int NPB = 256 / L;      // nodes per block
    int tid = threadIdx.x;
    int g = tid / L;
    int lane = tid % L;
    int node = blockIdx.x * NPB + g;
    int start = rowbeg[node], end = rowend[node];
    const float2* xw2 = (const float2*)xw;
    float accx = 0.f, accy = 0.f;
    for (int j = start; j < end; j += 16) {
        unsigned long long p[16];
        float2 v[16];
#pragma unroll
        for (int u = 0; u < 16; ++u) {
            int jj = j + u;
            int idx = jj < end ? jj : end - 1;   // clamp: row non-empty here
            p[u] = __builtin_nontemporal_load((const unsigned long long*)(edata + idx));
        }
#pragma unroll
        for (int u = 0; u < 16; ++u) {
            int s = (int)(unsigned)(p[u] & 0xffffffffu);
            v[u] = xw2[(size_t)s * L + lane];
        }
#pragma unroll
        for (int u = 0; u < 16; ++u) {
            float w = (j + u < end) ? __int_as_float((int)(p[u] >> 32)) : 0.f;
            accx = fmaf(w, v[u].x, accx);
            accy = fmaf(w, v[u].y, accy);
        }
    }
    float2 av = ((const float2*)a)[(size_t)node * L + lane];
    float2 bv = ((const float2*)bias)[lane];
    float rx = av.x + accx + bv.x;
    float ry = av.y + accy + bv.y;
    float2 r;
    r.x = rx > 0.f ? rx : 0.f;
    r.y = ry > 0.f ? ry : 0.f;
    ((float2*)out)[(size_t)node * L + lane] = r;
}

// ---------------- collapsed FC head ----------------
__global__ __launch_bounds__(256) void k_w23(const float* __restrict__ fc2w,
                                             const float* __restrict__ fc3w,
                                             float* __restrict__ w23) {
    int gid = blockIdx.x * 256 + threadIdx.x;
    if (gid >= F1 * NC) return;
    int r = gid / NC, c = gid % NC;
    float acc = 0.f;
    for (int j = 0; j < F2; ++j) acc = fmaf(fc2w[r * F2 + j], fc3w[j * NC + c], acc);
    w23[gid] = acc;
}

__global__ __launch_bounds__(64) void k_bc(const float* __restrict__ fc1b,
                                           const float* __restrict__ fc2b,
                                           const float* __restrict__ fc3b,
                                           const float* __restrict__ fc3w,
                                           const float* __restrict__ w23,
                                           float* __restrict__ bc) {
    int c = threadIdx.x;
    if (c >= NC) return;
    float acc = fc3b[c];
    for (int k = 0; k < F1; ++k) acc = fmaf(fc1b[k], w23[k * NC + c], acc);
    for (int j = 0; j < F2; ++j) acc = fmaf(fc2b[j], fc3w[j * NC + c], acc);
    bc[c] = acc;
}

__global__ __launch_bounds__(256) void k_t1(const float* __restrict__ fc1w,
                                            const float* __restrict__ fc2w,
                                            float* __restrict__ t1) {
    int c = threadIdx.x & 127;
    int rh = threadIdx.x >> 7;
    int r0 = blockIdx.x * 16 + rh;
    float acc[8];
#pragma unroll
    for (int rr = 0; rr < 8; ++rr) acc[rr] = 0.f;
    for (int k = 0; k < F1; ++k) {
        float wv = fc2w[k * F2 + c];
#pragma unroll
        for (int rr = 0; rr < 8; ++rr)
            acc[rr] = fmaf(fc1w[(r0 + rr * 2) * F1 + k], wv, acc[rr]);
    }
#pragma unroll
    for (int rr = 0; rr < 8; ++rr) t1[(r0 + rr * 2) * F2 + c] = acc[rr];
}

__global__ __launch_bounds__(256) void k_wc(const float* __restrict__ t1,
                                            const float* __restrict__ fc3w,
                                            float* __restrict__ wc) {
    int gid = blockIdx.x * 256 + threadIdx.x;
    int r = gid >> 4, c = gid & 15;
    if (c >= NC) return;
    float acc = 0.f;
    for (int j = 0; j < F2; ++j) acc = fmaf(t1[r * F2 + j], fc3w[j * NC + c], acc);
    wc[r * NC + c] = acc;
}

__global__ __launch_bounds__(256) void k_out(const float* __restrict__ h3,
                                             const float* __restrict__ wc,
                                             const float* __restrict__ bc,
                                             float* __restrict__ out) {
    __shared__ float red[256 * 10];
    int g = blockIdx.x, tid = threadIdx.x;
    float acc[NC];
#pragma unroll
    for (int c = 0; c < NC; ++c) acc[c] = 0.f;
    for (int k = tid; k < FIN; k += 256) {
        float hv = h3[(size_t)g * FIN + k];
#pragma unroll
        for (int c = 0; c < NC; ++c) acc[c] = fmaf(hv, wc[k * NC + c], acc[c]);
    }
#pragma unroll
    for (int c = 0; c < NC; ++c) red[tid * 10 + c] = acc[c];
    __syncthreads();
    for (int s = 128; s > 0; s >>= 1) {
        if (tid < s) {
#pragma unroll
            for (int c = 0; c < NC; ++c) red[tid * 10 + c] += red[(tid + s) * 10 + c];
        }
        __syncthreads();
    }
    if (tid < NC) out[g * NC + tid] = red[tid] + bc[tid];
}

// ---------------- launch ----------------

extern "C" void kernel_launch(void* const* d_in, const int* in_sizes, int n_in,
                              void* d_out, int out_size, void* d_ws, size_t ws_size,
                              hipStream_t stream) {
    const float* x    = (const float*)d_in[0];
    const int*   ei   = (const int*)d_in[1];
    const float* ew   = (const float*)d_in[2];
    const float* W1_0 = (const float*)d_in[3];
    const float* W1_1 = (const float*)d_in[4];
    const float* b1   = (const float*)d_in[5];
    const float* W2_0 = (const float*)d_in[6];
    const float* W2_1 = (const float*)d_in[7];
    const float* b2   = (const float*)d_in[8];
    const float* W3_0 = (const float*)d_in[9];
    const float* W3_1 = (const float*)d_in[10];
    const float* b3   = (const float*)d_in[11];
    const float* fc1w = (const float*)d_in[12];
    const float* fc1b = (const float*)d_in[13];
    const float* fc2w = (const float*)d_in[14];
    const float* fc2b = (const float*)d_in[15];
    const float* fc3w = (const float*)d_in[16];
    const float* fc3b = (const float*)d_in[17];
    float* out = (float*)d_out;
    float* ws  = (float*)d_ws;

    const int* src = ei;        // edge_index[0]
    const int* dst = ei + NE;   // edge_index[1]

    // workspace layout (all regions 8B-aligned):
    //   dbuck [NBUCK*CAP int2]  -- dead after k_fin; A,B alias here (26.2MB <= 29.5MB)
    //   sbuck [NBUCK*CAP int2]  -- dead after k_deg2; edata aliases here
    //   D     [NN*HH floats]
    const size_t REG = (size_t)NBUCK * CAP;
    float* dinv  = ws;                         // [NN]
    int2*  dbuck = (int2*)(dinv + NN);         // [REG]
    int2*  sbuck = dbuck + REG;                // [REG]
    int2*  edata = sbuck;                      // alias
    float* D     = (float*)(sbuck + REG);      // [NN*HH]
    int*   rowbeg = (int*)(D + (size_t)NN * HH);  // [NN]
    int*   rowend = rowbeg + NN;               // [NN]
    int*   scur   = rowend + NN;               // [NBUCK] (pad to even)
    int*   dcur   = scur + ((NBUCK + 1) & ~1); // [NBUCK]
    float* w23    = (float*)(dcur + ((NBUCK + 1) & ~1));  // [256*9]
    float* bc     = w23 + F1 * NC;             // [9]

    float* A = (float*)dbuck;                  // [NN*HH] alias
    float* B = A + (size_t)NN * HH;            // [NN*HH] alias

    // graph preprocessing: dual partition -> dinv -> CSR finalize
    k_init<<<1, 256, 0, stream>>>(scur, dcur);
    k_part<0><<<NE / TILE, 256, 0, stream>>>(src, dst, ew, scur, sbuck);
    k_part<1><<<NE / TILE, 256, 0, stream>>>(src, dst, ew, dcur, dbuck);
    k_deg2<<<NBUCK, 512, 0, stream>>>(scur, sbuck, dinv);
    k_fin<<<NBUCK, 512, 0, stream>>>(dcur, dbuck, dinv, edata, rowbeg, rowend);

    // layer 1: 64 -> 32
    k_dual_gemm<TT, HH><<<NN / 256, 256, 0, stream>>>(x, W1_0, W1_1, A, B);
    k_gather<HH><<<NN / 16, 256, 0, stream>>>(rowbeg, rowend, edata, B, A, b1, D);

    // layer 2: 32 -> 32
    k_dual_gemm<HH, HH><<<NN / 256, 256, 0, stream>>>(D, W2_0, W2_1, A, B);
    k_gather<HH><<<NN / 16, 256, 0, stream>>>(rowbeg, rowend, edata, B, A, b2, D);

    // layer 3: 32 -> 16
    k_dual_gemm<HH, BSC><<<NN / 256, 256, 0, stream>>>(D, W3_0, W3_1, A, B);
    k_gather<BSC><<<NN / 32, 256, 0, stream>>>(rowbeg, rowend, edata, B, A, b3, D); // h3 in D

    // collapsed FC head
    k_w23<<<(F1 * NC + 255) / 256, 256, 0, stream>>>(fc2w, fc3w, w23);
    k_bc<<<1, 64, 0, stream>>>(fc1b, fc2b, fc3b, fc3w, w23, bc);
    float* T1 = A;   // [6400,128]
    k_t1<<<FIN / 16, 256, 0, stream>>>(fc1w, fc2w, T1);
    float* Wc = B;   // [6400,9]
    k_wc<<<FIN * 16 / 256, 256, 0, stream>>>(T1, fc3w, Wc);
    k_out<<<NG, 256, 0, stream>>>(D, Wc, bc, out);
}

// Round 10
// 632.715 us; speedup vs baseline: 1.0631x; 1.0631x over previous
//
#include <hip/hip_runtime.h>

// Problem constants
#define NN   102400      // nodes
#define NE   3276800     // edges
#define TT   64          // in channels
#define HH   32          // hidden
#define BSC  16          // conv3 out channels
#define NG   256         // graphs
#define NC   9           // classes
#define F1   256         // fc1 out
#define F2   128         // fc2 out
#define FIN  6400        // 400*16, fc1 in

#define NBUCK 200        // NN / 512 buckets (by node>>9)
#define CAP   18432      // slots per bucket region (mean 16384, +16 sigma)
#define TILE  8192       // edges per partition workgroup (NE/TILE = 400 wgs)

// ---------------- bucket cursor init ----------------

__global__ __launch_bounds__(256) void k_init(int* __restrict__ scur,
                                              int* __restrict__ dcur) {
    int t = threadIdx.x;
    if (t < NBUCK) { scur[t] = t * CAP; dcur[t] = t * CAP; }
}

// ---------------- LDS-staged partition by (src|dst)>>9 ----------------
// MODE 0: bucket by src, payload {src&511, ew}
// MODE 1: bucket by dst, payload {(src<<9)|(dst&511), ew}
template<int MODE>
__global__ __launch_bounds__(256) void k_part(const int* __restrict__ src,
                                              const int* __restrict__ dst,
                                              const float* __restrict__ ew,
                                              int* __restrict__ gcur,
                                              int2* __restrict__ outbuf) {
    __shared__ int hist[256];
    __shared__ int base[256];
    __shared__ int cur[256];
    __shared__ int gpos[256];
    __shared__ int2 stage[TILE];
    __shared__ unsigned char bkt[TILE];

    int t = threadIdx.x;
    int e0 = blockIdx.x * TILE;

    hist[t] = 0;
    __syncthreads();
    // phase 1: tile histogram
#pragma unroll
    for (int i = 0; i < TILE / 256; ++i) {
        int e = e0 + i * 256 + t;
        int key = MODE ? dst[e] : src[e];
        atomicAdd(&hist[key >> 9], 1);
    }
    __syncthreads();
    // phase 2: exclusive scan -> base
    int h = hist[t];
    base[t] = h;
    __syncthreads();
    for (int off = 1; off < 256; off <<= 1) {
        int add = (t >= off) ? base[t - off] : 0;
        __syncthreads();
        base[t] += add;
        __syncthreads();
    }
    int excl = base[t] - h;
    __syncthreads();
    base[t] = excl;
    cur[t] = excl;
    __syncthreads();
    // phase 3: place into LDS
#pragma unroll
    for (int i = 0; i < TILE / 256; ++i) {
        int e = e0 + i * 256 + t;
        int s = src[e];
        int w = __float_as_int(ew[e]);
        int key, pack;
        if (MODE) { int d = dst[e]; key = d; pack = (s << 9) | (d & 511); }
        else      { key = s; pack = s & 511; }
        int b = key >> 9;
        int p = atomicAdd(&cur[b], 1);
        stage[p] = make_int2(pack, w);
        bkt[p] = (unsigned char)b;
    }
    __syncthreads();
    // phase 4: claim contiguous global ranges in this bucket's region
    if (t < NBUCK && h > 0) gpos[t] = atomicAdd(&gcur[t], h);
    __syncthreads();
    // phase 5: coalesced flush
#pragma unroll
    for (int i = 0; i < TILE / 256; ++i) {
        int p = i * 256 + t;
        int b = bkt[p];
        outbuf[gpos[b] + (p - base[b])] = stage[p];
    }
}

// ---------------- per-src-bucket weighted degree -> dinv (LDS histogram) ---

__global__ __launch_bounds__(512) void k_deg2(const int* __restrict__ scur,
                                              const int2* __restrict__ sbuck,
                                              float* __restrict__ dinv) {
    __shared__ float acc[512];
    int b = blockIdx.x, t = threadIdx.x;
    acc[t] = 0.f;
    __syncthreads();
    int lo = b * CAP, hi = scur[b];
    for (int j = lo + t; j < hi; j += 512) {
        int2 e = sbuck[j];
        atomicAdd(&acc[e.x], __int_as_float(e.y));
    }
    __syncthreads();
    float v = acc[t];
    dinv[b * 512 + t] = v > 0.f ? rsqrtf(v) : 0.f;
}

// ---------------- per-dst-bucket CSR finalize (LDS hist+scan+cursors) ------
// edata[slot] = {src, lapw}; rowbeg/rowend delimit each node's edges.

__global__ __launch_bounds__(512) void k_fin(const int* __restrict__ dcur,
                                             const int2* __restrict__ dbuck,
                                             const float* __restrict__ dinv,
                                             int2* __restrict__ edata,
                                             int* __restrict__ rowbeg,
                                             int* __restrict__ rowend) {
    __shared__ float dl[512];
    __shared__ int cnt[512];
    __shared__ int base[512];
    __shared__ int cur[512];
    int b = blockIdx.x, t = threadIdx.x;
    dl[t] = dinv[b * 512 + t];
    cnt[t] = 0;
    __syncthreads();
    int lo = b * CAP, hi = dcur[b];
    for (int j = lo + t; j < hi; j += 512)
        atomicAdd(&cnt[dbuck[j].x & 511], 1);
    __syncthreads();
    int h = cnt[t];
    base[t] = h;
    __syncthreads();
    for (int off = 1; off < 512; off <<= 1) {
        int add = (t >= off) ? base[t - off] : 0;
        __syncthreads();
        base[t] += add;
        __syncthreads();
    }
    int beg = lo + base[t] - h;
    rowbeg[b * 512 + t] = beg;
    rowend[b * 512 + t] = beg + h;
    cur[t] = beg;
    __syncthreads();
    for (int j = lo + t; j < hi; j += 512) {
        int2 e = dbuck[j];
        int dlow = e.x & 511;
        int s = e.x >> 9;
        float lw = -dinv[s] * __int_as_float(e.y) * dl[dlow];
        int slot = atomicAdd(&cur[dlow], 1);
        edata[slot] = make_int2(s, __float_as_int(lw));
    }
}

// ---------------- per-node dual GEMM (h@W0 and h@W1) ----------------
template<int CIN, int COUT>
__global__ __launch_bounds__(256) void k_dual_gemm(const float* __restrict__ in,
                                                   const float* __restrict__ W0,
                                                   const float* __restrict__ W1,
                                                   float* __restrict__ o0,
                                                   float* __restrict__ o1) {
    int node = blockIdx.x * 256 + threadIdx.x;
    const float* row = in + (size_t)node * CIN;
    float a0[COUT], a1[COUT];
#pragma unroll
    for (int c = 0; c < COUT; ++c) { a0[c] = 0.f; a1[c] = 0.f; }
    for (int k = 0; k < CIN; ++k) {
        float xv = row[k];
#pragma unroll
        for (int c = 0; c < COUT; ++c) {
            a0[c] = fmaf(xv, W0[k * COUT + c], a0[c]);
            a1[c] = fmaf(xv, W1[k * COUT + c], a1[c]);
        }
    }
#pragma unroll
    for (int c = 0; c < COUT; ++c) {
        o0[(size_t)node * COUT + c] = a0[c];
        o1[(size_t)node * COUT + c] = a1[c];
    }
}

// ---------------- CSR gather fused with bias+relu (round-8 proven form) ----
// out[n,c] = relu(a[n,c] + sum_e lapw_e * xw[src_e, c] + bias[c])
// float2 per lane (C/2 lanes per edge), 8-deep load pipeline.
template<int C>
__global__ __launch_bounds__(256) void k_gather(const int* __restrict__ rowbeg,
                                                const int* __restrict__ rowend,
                                                const int2* __restrict__ edata,
                                                const float* __restrict__ xw,
                                                const float* __restrict__ a,
                                                const float* __restrict__ bias,
                                                float* __restrict__ out) {
    constexpr int L = C / 2;          // lanes per edge (float2 each)
    constexpr int NPB = 256 / L;      // nodes per block
    int tid = threadIdx.x;
    int g = tid / L;
    int lane = tid % L;
    int node = blockIdx.x * NPB + g;
    int start = rowbeg[node], end = rowend[node];
    const float2* xw2 = (const float2*)xw;
    float accx = 0.f, accy = 0.f;
    int j = start;
    for (; j + 7 < end; j += 8) {
        int2 e[8];
        float2 v[8];
#pragma unroll
        for (int u = 0; u < 8; ++u) e[u] = edata[j + u];
#pragma unroll
        for (int u = 0; u < 8; ++u) v[u] = xw2[(size_t)e[u].x * L + lane];
#pragma unroll
        for (int u = 0; u < 8; ++u) {
            float w = __int_as_float(e[u].y);
            accx = fmaf(w, v[u].x, accx);
            accy = fmaf(w, v[u].y, accy);
        }
    }
    for (; j < end; ++j) {
        int2 e0 = edata[j];
        float2 v0 = xw2[(size_t)e0.x * L + lane];
        float w = __int_as_float(e0.y);
        accx = fmaf(w, v0.x, accx);
        accy = fmaf(w, v0.y, accy);
    }
    float2 av = ((const float2*)a)[(size_t)node * L + lane];
    float2 bv = ((const float2*)bias)[lane];
    float rx = av.x + accx + bv.x;
    float ry = av.y + accy + bv.y;
    float2 r;
    r.x = rx > 0.f ? rx : 0.f;
    r.y = ry > 0.f ? ry : 0.f;
    ((float2*)out)[(size_t)node * L + lane] = r;
}

// ---------------- fused: layer-2 gather + bias/relu + layer-3 dual GEMM ----
// h2 = relu(a + gather + bias) held as float2/lane across 16-lane group;
// epilogue computes A3 = h2@W0, B3 = h2@W1 (W: [32][16]) via shfl rotation.
__global__ __launch_bounds__(256) void k_gather_gemm32(
        const int* __restrict__ rowbeg, const int* __restrict__ rowend,
        const int2* __restrict__ edata,
        const float* __restrict__ xw, const float* __restrict__ a,
        const float* __restrict__ bias,
        const float* __restrict__ W0, const float* __restrict__ W1,
        float* __restrict__ outA, float* __restrict__ outB) {
    constexpr int L = 16;             // lanes per node (float2 each, C=32)
    constexpr int NPB = 256 / L;      // 16 nodes per block
    int tid = threadIdx.x;
    int g = tid / L;
    int lane = tid % L;
    int node = blockIdx.x * NPB + g;
    int start = rowbeg[node], end = rowend[node];
    const float2* xw2 = (const float2*)xw;
    float accx = 0.f, accy = 0.f;
    int j = start;
    for (; j + 7 < end; j += 8) {
        int2 e[8];
        float2 v[8];
#pragma unroll
        for (int u = 0; u < 8; ++u) e[u] = edata[j + u];
#pragma unroll
        for (int u = 0; u < 8; ++u) v[u] = xw2[(size_t)e[u].x * L + lane];
#pragma unroll
        for (int u = 0; u < 8; ++u) {
            float w = __int_as_float(e[u].y);
            accx = fmaf(w, v[u].x, accx);
            accy = fmaf(w, v[u].y, accy);
        }
    }
    for (; j < end; ++j) {
        int2 e0 = edata[j];
        float2 v0 = xw2[(size_t)e0.x * L + lane];
        float w = __int_as_float(e0.y);
        accx = fmaf(w, v0.x, accx);
        accy = fmaf(w, v0.y, accy);
    }
    float2 av = ((const float2*)a)[(size_t)node * L + lane];
    float2 bv = ((const float2*)bias)[lane];
    float h0 = av.x + accx + bv.x;  h0 = h0 > 0.f ? h0 : 0.f;   // h2[2*lane]
    float h1 = av.y + accy + bv.y;  h1 = h1 > 0.f ? h1 : 0.f;   // h2[2*lane+1]
    // epilogue: a3 = sum_k h2[k]*W0[k][lane], b3 likewise (W row-major [32][16])
    float a3 = 0.f, b3 = 0.f;
#pragma unroll
    for (int r = 0; r < 16; ++r) {
        float hx = __shfl_xor(h0, r, 16);   // h2[2m], m = lane^r
        float hy = __shfl_xor(h1, r, 16);   // h2[2m+1]
        int m = lane ^ r;
        a3 = fmaf(hx, W0[(2 * m) * 16 + lane], a3);
        a3 = fmaf(hy, W0[(2 * m + 1) * 16 + lane], a3);
        b3 = fmaf(hx, W1[(2 * m) * 16 + lane], b3);
        b3 = fmaf(hy, W1[(2 * m + 1) * 16 + lane], b3);
    }
    outA[(size_t)node * 16 + lane] = a3;
    outB[(size_t)node * 16 + lane] = b3;
}

// ---------------- collapsed FC head ----------------
__global__ __launch_bounds__(256) void k_w23(const float* __restrict__ fc2w,
                                             const float* __restrict__ fc3w,
                                             float* __restrict__ w23) {
    int gid = blockIdx.x * 256 + threadIdx.x;
    if (gid >= F1 * NC) return;
    int r = gid / NC, c = gid % NC;
    float acc = 0.f;
    for (int j = 0; j < F2; ++j) acc = fmaf(fc2w[r * F2 + j], fc3w[j * NC + c], acc);
    w23[gid] = acc;
}

__global__ __launch_bounds__(64) void k_bc(const float* __restrict__ fc1b,
                                           const float* __restrict__ fc2b,
                                           const float* __restrict__ fc3b,
                                           const float* __restrict__ fc3w,
                                           const float* __restrict__ w23,
                                           float* __restrict__ bc) {
    int c = threadIdx.x;
    if (c >= NC) return;
    float acc = fc3b[c];
    for (int k = 0; k < F1; ++k) acc = fmaf(fc1b[k], w23[k * NC + c], acc);
    for (int j = 0; j < F2; ++j) acc = fmaf(fc2b[j], fc3w[j * NC + c], acc);
    bc[c] = acc;
}

__global__ __launch_bounds__(256) void k_t1(const float* __restrict__ fc1w,
                                            const float* __restrict__ fc2w,
                                            float* __restrict__ t1) {
    int c = threadIdx.x & 127;
    int rh = threadIdx.x >> 7;
    int r0 = blockIdx.x * 16 + rh;
    float acc[8];
#pragma unroll
    for (int rr = 0; rr < 8; ++rr) acc[rr] = 0.f;
    for (int k = 0; k < F1; ++k) {
        float wv = fc2w[k * F2 + c];
#pragma unroll
        for (int rr = 0; rr < 8; ++rr)
            acc[rr] = fmaf(fc1w[(r0 + rr * 2) * F1 + k], wv, acc[rr]);
    }
#pragma unroll
    for (int rr = 0; rr < 8; ++rr) t1[(r0 + rr * 2) * F2 + c] = acc[rr];
}

__global__ __launch_bounds__(256) void k_wc(const float* __restrict__ t1,
                                            const float* __restrict__ fc3w,
                                            float* __restrict__ wc) {
    int gid = blockIdx.x * 256 + threadIdx.x;
    int r = gid >> 4, c = gid & 15;
    if (c >= NC) return;
    float acc = 0.f;
    for (int j = 0; j < F2; ++j) acc = fmaf(t1[r * F2 + j], fc3w[j * NC + c], acc);
    wc[r * NC + c] = acc;
}

__global__ __launch_bounds__(256) void k_out(const float* __restrict__ h3,
                                             const float* __restrict__ wc,
                                             const float* __restrict__ bc,
                                             float* __restrict__ out) {
    __shared__ float red[256 * 10];
    int g = blockIdx.x, tid = threadIdx.x;
    float acc[NC];
#pragma unroll
    for (int c = 0; c < NC; ++c) acc[c] = 0.f;
    for (int k = tid; k < FIN; k += 256) {
        float hv = h3[(size_t)g * FIN + k];
#pragma unroll
        for (int c = 0; c < NC; ++c) acc[c] = fmaf(hv, wc[k * NC + c], acc[c]);
    }
#pragma unroll
    for (int c = 0; c < NC; ++c) red[tid * 10 + c] = acc[c];
    __syncthreads();
    for (int s = 128; s > 0; s >>= 1) {
        if (tid < s) {
#pragma unroll
            for (int c = 0; c < NC; ++c) red[tid * 10 + c] += red[(tid + s) * 10 + c];
        }
        __syncthreads();
    }
    if (tid < NC) out[g * NC + tid] = red[tid] + bc[tid];
}

// ---------------- launch ----------------

extern "C" void kernel_launch(void* const* d_in, const int* in_sizes, int n_in,
                              void* d_out, int out_size, void* d_ws, size_t ws_size,
                              hipStream_t stream) {
    const float* x    = (const float*)d_in[0];
    const int*   ei   = (const int*)d_in[1];
    const float* ew   = (const float*)d_in[2];
    const float* W1_0 = (const float*)d_in[3];
    const float* W1_1 = (const float*)d_in[4];
    const float* b1   = (const float*)d_in[5];
    const float* W2_0 = (const float*)d_in[6];
    const float* W2_1 = (const float*)d_in[7];
    const float* b2   = (const float*)d_in[8];
    const float* W3_0 = (const float*)d_in[9];
    const float* W3_1 = (const float*)d_in[10];
    const float* b3   = (const float*)d_in[11];
    const float* fc1w = (const float*)d_in[12];
    const float* fc1b = (const float*)d_in[13];
    const float* fc2w = (const float*)d_in[14];
    const float* fc2b = (const float*)d_in[15];
    const float* fc3w = (const float*)d_in[16];
    const float* fc3b = (const float*)d_in[17];
    float* out = (float*)d_out;
    float* ws  = (float*)d_ws;

    const int* src = ei;        // edge_index[0]
    const int* dst = ei + NE;   // edge_index[1]

    // workspace layout (same footprint as round 8, all regions 8B-aligned):
    //   dbuck [REG int2]  -- dead after k_fin; A1,B1 alias; later A2,B2; then h3/T1/Wc
    //   sbuck [REG int2]  -- dead after k_deg2; edata aliases here
    //   Dreg  [NN*HH floats] -- h1; later A3,B3 (exactly NN*32 floats)
    const size_t REG = (size_t)NBUCK * CAP;
    float* dinv  = ws;                         // [NN]
    int2*  dbuck = (int2*)(dinv + NN);         // [REG]
    int2*  sbuck = dbuck + REG;                // [REG]
    int2*  edata = sbuck;                      // alias
    float* Dreg  = (float*)(sbuck + REG);      // [NN*HH]
    int*   rowbeg = (int*)(Dreg + (size_t)NN * HH);  // [NN]
    int*   rowend = rowbeg + NN;               // [NN]
    int*   scur   = rowend + NN;               // [NBUCK] (pad to even)
    int*   dcur   = scur + ((NBUCK + 1) & ~1); // [NBUCK]
    float* w23    = (float*)(dcur + ((NBUCK + 1) & ~1));  // [256*9]
    float* bc     = w23 + F1 * NC;             // [9]

    float* A = (float*)dbuck;                  // [NN*HH] alias (A1 / A2)
    float* B = A + (size_t)NN * HH;            // [NN*HH] alias (B1 / B2)
    float* A3 = Dreg;                          // [NN*16]
    float* B3 = Dreg + (size_t)NN * BSC;       // [NN*16]
    float* h3 = (float*)dbuck;                 // [NN*16] (dbuck dead after FS2)
    float* T1 = (float*)dbuck + 2000000;       // [6400*128] well past h3
    float* Wc = (float*)dbuck + 3000000;       // [6400*9]

    // graph preprocessing: dual partition -> dinv -> CSR finalize
    k_init<<<1, 256, 0, stream>>>(scur, dcur);
    k_part<0><<<NE / TILE, 256, 0, stream>>>(src, dst, ew, scur, sbuck);
    k_part<1><<<NE / TILE, 256, 0, stream>>>(src, dst, ew, dcur, dbuck);
    k_deg2<<<NBUCK, 512, 0, stream>>>(scur, sbuck, dinv);
    k_fin<<<NBUCK, 512, 0, stream>>>(dcur, dbuck, dinv, edata, rowbeg, rowend);

    // layer 1: 64 -> 32   (dbuck dead after k_fin -> A,B live there)
    k_dual_gemm<TT, HH><<<NN / 256, 256, 0, stream>>>(x, W1_0, W1_1, A, B);
    k_gather<HH><<<NN / 16, 256, 0, stream>>>(rowbeg, rowend, edata, B, A, b1, Dreg); // h1

    // layer 2 gemm: h1 -> A2,B2 (overwrites A1,B1; dead)
    k_dual_gemm<HH, HH><<<NN / 256, 256, 0, stream>>>(Dreg, W2_0, W2_1, A, B);
    // fused layer-2 gather + layer-3 gemm: -> A3,B3 (overwrites h1; dead)
    k_gather_gemm32<<<NN / 16, 256, 0, stream>>>(rowbeg, rowend, edata, B, A, b2,
                                                 W3_0, W3_1, A3, B3);
    // layer 3 gather: -> h3 (into dead dbuck space)
    k_gather<BSC><<<NN / 32, 256, 0, stream>>>(rowbeg, rowend, edata, B3, A3, b3, h3);

    // collapsed FC head
    k_w23<<<(F1 * NC + 255) / 256, 256, 0, stream>>>(fc2w, fc3w, w23);
    k_bc<<<1, 64, 0, stream>>>(fc1b, fc2b, fc3b, fc3w, w23, bc);
    k_t1<<<FIN / 16, 256, 0, stream>>>(fc1w, fc2w, T1);
    k_wc<<<FIN * 16 / 256, 256, 0, stream>>>(T1, fc3w, Wc);
    k_out<<<NG, 256, 0, stream>>>(h3, Wc, bc, out);
}

// Round 11
// 570.080 us; speedup vs baseline: 1.1799x; 1.1099x over previous
//
#include <hip/hip_runtime.h>

// Problem constants
#define NN   102400      // nodes
#define NE   3276800     // edges
#define TT   64          // in channels
#define HH   32          // hidden
#define BSC  16          // conv3 out channels
#define NG   256         // graphs
#define NC   9           // classes
#define F1   256         // fc1 out
#define F2   128         // fc2 out
#define FIN  6400        // 400*16, fc1 in

#define NBUCK 200        // NN / 512 buckets (by node>>9)
#define CAP   18432      // slots per bucket region (mean 16384, +16 sigma)
#define TILE  4096       // edges per partition workgroup (NE/TILE = 800 wgs; 40KB LDS -> 4 blk/CU)

// ---------------- bucket cursor init ----------------

__global__ __launch_bounds__(256) void k_init(int* __restrict__ scur,
                                              int* __restrict__ dcur) {
    int t = threadIdx.x;
    if (t < NBUCK) { scur[t] = t * CAP; dcur[t] = t * CAP; }
}

// ---------------- LDS-staged partition by (src|dst)>>9 ----------------
// MODE 0: bucket by src, payload {src&511, ew}
// MODE 1: bucket by dst, payload {(src<<9)|(dst&511), ew}
template<int MODE>
__global__ __launch_bounds__(256) void k_part(const int* __restrict__ src,
                                              const int* __restrict__ dst,
                                              const float* __restrict__ ew,
                                              int* __restrict__ gcur,
                                              int2* __restrict__ outbuf) {
    __shared__ int hist[256];
    __shared__ int base[256];
    __shared__ int cur[256];
    __shared__ int gpos[256];
    __shared__ int2 stage[TILE];
    __shared__ unsigned char bkt[TILE];

    int t = threadIdx.x;
    int e0 = blockIdx.x * TILE;

    hist[t] = 0;
    __syncthreads();
    // phase 1: tile histogram
#pragma unroll
    for (int i = 0; i < TILE / 256; ++i) {
        int e = e0 + i * 256 + t;
        int key = MODE ? dst[e] : src[e];
        atomicAdd(&hist[key >> 9], 1);
    }
    __syncthreads();
    // phase 2: exclusive scan -> base
    int h = hist[t];
    base[t] = h;
    __syncthreads();
    for (int off = 1; off < 256; off <<= 1) {
        int add = (t >= off) ? base[t - off] : 0;
        __syncthreads();
        base[t] += add;
        __syncthreads();
    }
    int excl = base[t] - h;
    __syncthreads();
    base[t] = excl;
    cur[t] = excl;
    __syncthreads();
    // phase 3: place into LDS
#pragma unroll
    for (int i = 0; i < TILE / 256; ++i) {
        int e = e0 + i * 256 + t;
        int s = src[e];
        int w = __float_as_int(ew[e]);
        int key, pack;
        if (MODE) { int d = dst[e]; key = d; pack = (s << 9) | (d & 511); }
        else      { key = s; pack = s & 511; }
        int b = key >> 9;
        int p = atomicAdd(&cur[b], 1);
        stage[p] = make_int2(pack, w);
        bkt[p] = (unsigned char)b;
    }
    __syncthreads();
    // phase 4: claim contiguous global ranges in this bucket's region
    if (t < NBUCK && h > 0) gpos[t] = atomicAdd(&gcur[t], h);
    __syncthreads();
    // phase 5: coalesced flush
#pragma unroll
    for (int i = 0; i < TILE / 256; ++i) {
        int p = i * 256 + t;
        int b = bkt[p];
        outbuf[gpos[b] + (p - base[b])] = stage[p];
    }
}

// ---------------- per-src-bucket weighted degree -> dinv (LDS histogram) ---

__global__ __launch_bounds__(512) void k_deg2(const int* __restrict__ scur,
                                              const int2* __restrict__ sbuck,
                                              float* __restrict__ dinv) {
    __shared__ float acc[512];
    int b = blockIdx.x, t = threadIdx.x;
    acc[t] = 0.f;
    __syncthreads();
    int lo = b * CAP, hi = scur[b];
    for (int j = lo + t; j < hi; j += 512) {
        int2 e = sbuck[j];
        atomicAdd(&acc[e.x], __int_as_float(e.y));
    }
    __syncthreads();
    float v = acc[t];
    dinv[b * 512 + t] = v > 0.f ? rsqrtf(v) : 0.f;
}

// ---------------- per-dst-bucket CSR finalize (LDS hist+scan+cursors) ------
// Factored normalization: edata[slot] = {src, ew} (dinv applied elsewhere).

__global__ __launch_bounds__(512) void k_fin(const int* __restrict__ dcur,
                                             const int2* __restrict__ dbuck,
                                             int2* __restrict__ edata,
                                             int* __restrict__ rowbeg,
                                             int* __restrict__ rowend) {
    __shared__ int cnt[512];
    __shared__ int base[512];
    __shared__ int cur[512];
    int b = blockIdx.x, t = threadIdx.x;
    cnt[t] = 0;
    __syncthreads();
    int lo = b * CAP, hi = dcur[b];
    for (int j = lo + t; j < hi; j += 512)
        atomicAdd(&cnt[dbuck[j].x & 511], 1);
    __syncthreads();
    int h = cnt[t];
    base[t] = h;
    __syncthreads();
    for (int off = 1; off < 512; off <<= 1) {
        int add = (t >= off) ? base[t - off] : 0;
        __syncthreads();
        base[t] += add;
        __syncthreads();
    }
    int beg = lo + base[t] - h;
    rowbeg[b * 512 + t] = beg;
    rowend[b * 512 + t] = beg + h;
    cur[t] = beg;
    __syncthreads();
    for (int j = lo + t; j < hi; j += 512) {
        int2 e = dbuck[j];
        int slot = atomicAdd(&cur[e.x & 511], 1);
        edata[slot] = make_int2(e.x >> 9, e.y);   // {src, ew bits}
    }
}

// ---------------- per-node dual GEMM: o0 = h@W0, o1 = dinv[n]*(h@W1) -------
// float4 row loads/stores; W reads are lane-uniform (scalarized).
template<int CIN, int COUT>
__global__ __launch_bounds__(256) void k_dual_gemm(const float* __restrict__ in,
                                                   const float* __restrict__ W0,
                                                   const float* __restrict__ W1,
                                                   const float* __restrict__ dinv,
                                                   float* __restrict__ o0,
                                                   float* __restrict__ o1) {
    int node = blockIdx.x * 256 + threadIdx.x;
    const float4* row4 = (const float4*)(in + (size_t)node * CIN);
    float a0[COUT], a1[COUT];
#pragma unroll
    for (int c = 0; c < COUT; ++c) { a0[c] = 0.f; a1[c] = 0.f; }
    for (int k4 = 0; k4 < CIN / 4; ++k4) {
        float4 x4 = row4[k4];
        float xs[4] = {x4.x, x4.y, x4.z, x4.w};
#pragma unroll
        for (int j = 0; j < 4; ++j) {
            int k = 4 * k4 + j;
#pragma unroll
            for (int c = 0; c < COUT; ++c) {
                a0[c] = fmaf(xs[j], W0[k * COUT + c], a0[c]);
                a1[c] = fmaf(xs[j], W1[k * COUT + c], a1[c]);
            }
        }
    }
    float dv = dinv[node];
    float4* p0 = (float4*)(o0 + (size_t)node * COUT);
    float4* p1 = (float4*)(o1 + (size_t)node * COUT);
#pragma unroll
    for (int c4 = 0; c4 < COUT / 4; ++c4) {
        p0[c4] = make_float4(a0[4 * c4], a0[4 * c4 + 1], a0[4 * c4 + 2], a0[4 * c4 + 3]);
        p1[c4] = make_float4(a1[4 * c4] * dv, a1[4 * c4 + 1] * dv,
                             a1[4 * c4 + 2] * dv, a1[4 * c4 + 3] * dv);
    }
}

// ---------------- CSR gather fused with bias+relu (round-8 proven form) ----
// out[n,c] = relu(a[n,c] - dinv[n]*sum_e ew_e*xs[src_e,c] + bias[c])
// float2 per lane (C/2 lanes per edge), 8-deep load pipeline.
template<int C>
__global__ __launch_bounds__(256) void k_gather(const int* __restrict__ rowbeg,
                                                const int* __restrict__ rowend,
                                                const int2* __restrict__ edata,
                                                const float* __restrict__ xw,
                                                const float* __restrict__ a,
                                                const float* __restrict__ bias,
                                                const float* __restrict__ dinv,
                                                float* __restrict__ out) {
    constexpr int L = C / 2;          // lanes per edge (float2 each)
    constexpr int NPB = 256 / L;      // nodes per block
    int tid = threadIdx.x;
    int g = tid / L;
    int lane = tid % L;
    int node = blockIdx.x * NPB + g;
    int start = rowbeg[node], end = rowend[node];
    const float2* xw2 = (const float2*)xw;
    float accx = 0.f, accy = 0.f;
    int j = start;
    for (; j + 7 < end; j += 8) {
        int2 e[8];
        float2 v[8];
#pragma unroll
        for (int u = 0; u < 8; ++u) e[u] = edata[j + u];
#pragma unroll
        for (int u = 0; u < 8; ++u) v[u] = xw2[(size_t)e[u].x * L + lane];
#pragma unroll
        for (int u = 0; u < 8; ++u) {
            float w = __int_as_float(e[u].y);
            accx = fmaf(w, v[u].x, accx);
            accy = fmaf(w, v[u].y, accy);
        }
    }
    for (; j < end; ++j) {
        int2 e0 = edata[j];
        float2 v0 = xw2[(size_t)e0.x * L + lane];
        float w = __int_as_float(e0.y);
        accx = fmaf(w, v0.x, accx);
        accy = fmaf(w, v0.y, accy);
    }
    float dv = dinv[node];
    float2 av = ((const float2*)a)[(size_t)node * L + lane];
    float2 bv = ((const float2*)bias)[lane];
    float rx = av.x - dv * accx + bv.x;
    float ry = av.y - dv * accy + bv.y;
    float2 r;
    r.x = rx > 0.f ? rx : 0.f;
    r.y = ry > 0.f ? ry : 0.f;
    ((float2*)out)[(size_t)node * L + lane] = r;
}

// ---------------- collapsed FC head ----------------
__global__ __launch_bounds__(256) void k_w23(const float* __restrict__ fc2w,
                                             const float* __restrict__ fc3w,
                                             float* __restrict__ w23) {
    int gid = blockIdx.x * 256 + threadIdx.x;
    if (gid >= F1 * NC) return;
    int r = gid / NC, c = gid % NC;
    float acc = 0.f;
    for (int j = 0; j < F2; ++j) acc = fmaf(fc2w[r * F2 + j], fc3w[j * NC + c], acc);
    w23[gid] = acc;
}

__global__ __launch_bounds__(64) void k_bc(const float* __restrict__ fc1b,
                                           const float* __restrict__ fc2b,
                                           const float* __restrict__ fc3b,
                                           const float* __restrict__ fc3w,
                                           const float* __restrict__ w23,
                                           float* __restrict__ bc) {
    int c = threadIdx.x;
    if (c >= NC) return;
    float acc = fc3b[c];
    for (int k = 0; k < F1; ++k) acc = fmaf(fc1b[k], w23[k * NC + c], acc);
    for (int j = 0; j < F2; ++j) acc = fmaf(fc2b[j], fc3w[j * NC + c], acc);
    bc[c] = acc;
}

__global__ __launch_bounds__(256) void k_t1(const float* __restrict__ fc1w,
                                            const float* __restrict__ fc2w,
                                            float* __restrict__ t1) {
    int c = threadIdx.x & 127;
    int rh = threadIdx.x >> 7;
    int r0 = blockIdx.x * 16 + rh;
    float acc[8];
#pragma unroll
    for (int rr = 0; rr < 8; ++rr) acc[rr] = 0.f;
    for (int k = 0; k < F1; ++k) {
        float wv = fc2w[k * F2 + c];
#pragma unroll
        for (int rr = 0; rr < 8; ++rr)
            acc[rr] = fmaf(fc1w[(r0 + rr * 2) * F1 + k], wv, acc[rr]);
    }
#pragma unroll
    for (int rr = 0; rr < 8; ++rr) t1[(r0 + rr * 2) * F2 + c] = acc[rr];
}

__global__ __launch_bounds__(256) void k_wc(const float* __restrict__ t1,
                                            const float* __restrict__ fc3w,
                                            float* __restrict__ wc) {
    int gid = blockIdx.x * 256 + threadIdx.x;
    int r = gid >> 4, c = gid & 15;
    if (c >= NC) return;
    float acc = 0.f;
    for (int j = 0; j < F2; ++j) acc = fmaf(t1[r * F2 + j], fc3w[j * NC + c], acc);
    wc[r * NC + c] = acc;
}

__global__ __launch_bounds__(256) void k_out(const float* __restrict__ h3,
                                             const float* __restrict__ wc,
                                             const float* __restrict__ bc,
                                             float* __restrict__ out) {
    __shared__ float red[256 * 10];
    int g = blockIdx.x, tid = threadIdx.x;
    float acc[NC];
#pragma unroll
    for (int c = 0; c < NC; ++c) acc[c] = 0.f;
    for (int k = tid; k < FIN; k += 256) {
        float hv = h3[(size_t)g * FIN + k];
#pragma unroll
        for (int c = 0; c < NC; ++c) acc[c] = fmaf(hv, wc[k * NC + c], acc[c]);
    }
#pragma unroll
    for (int c = 0; c < NC; ++c) red[tid * 10 + c] = acc[c];
    __syncthreads();
    for (int s = 128; s > 0; s >>= 1) {
        if (tid < s) {
#pragma unroll
            for (int c = 0; c < NC; ++c) red[tid * 10 + c] += red[(tid + s) * 10 + c];
        }
        __syncthreads();
    }
    if (tid < NC) out[g * NC + tid] = red[tid] + bc[tid];
}

// ---------------- launch ----------------

extern "C" void kernel_launch(void* const* d_in, const int* in_sizes, int n_in,
                              void* d_out, int out_size, void* d_ws, size_t ws_size,
                              hipStream_t stream) {
    const float* x    = (const float*)d_in[0];
    const int*   ei   = (const int*)d_in[1];
    const float* ew   = (const float*)d_in[2];
    const float* W1_0 = (const float*)d_in[3];
    const float* W1_1 = (const float*)d_in[4];
    const float* b1   = (const float*)d_in[5];
    const float* W2_0 = (const float*)d_in[6];
    const float* W2_1 = (const float*)d_in[7];
    const float* b2   = (const float*)d_in[8];
    const float* W3_0 = (const float*)d_in[9];
    const float* W3_1 = (const float*)d_in[10];
    const float* b3   = (const float*)d_in[11];
    const float* fc1w = (const float*)d_in[12];
    const float* fc1b = (const float*)d_in[13];
    const float* fc2w = (const float*)d_in[14];
    const float* fc2b = (const float*)d_in[15];
    const float* fc3w = (const float*)d_in[16];
    const float* fc3b = (const float*)d_in[17];
    float* out = (float*)d_out;
    float* ws  = (float*)d_ws;

    const int* src = ei;        // edge_index[0]
    const int* dst = ei + NE;   // edge_index[1]

    // workspace layout (round-8 proven):
    //   dbuck [REG int2]  -- dead after k_fin; A,B alias (26.2MB <= 29.5MB)
    //   sbuck [REG int2]  -- dead after k_deg2; edata aliases here
    //   D     [NN*HH floats]
    const size_t REG = (size_t)NBUCK * CAP;
    float* dinv  = ws;                         // [NN]
    int2*  dbuck = (int2*)(dinv + NN);         // [REG]
    int2*  sbuck = dbuck + REG;                // [REG]
    int2*  edata = sbuck;                      // alias
    float* D     = (float*)(sbuck + REG);      // [NN*HH]
    int*   rowbeg = (int*)(D + (size_t)NN * HH);  // [NN]
    int*   rowend = rowbeg + NN;               // [NN]
    int*   scur   = rowend + NN;               // [NBUCK] (pad to even)
    int*   dcur   = scur + ((NBUCK + 1) & ~1); // [NBUCK]
    float* w23    = (float*)(dcur + ((NBUCK + 1) & ~1));  // [256*9]
    float* bc     = w23 + F1 * NC;             // [9]

    float* A = (float*)dbuck;                  // [NN*HH] alias
    float* B = A + (size_t)NN * HH;            // [NN*HH] alias

    // graph preprocessing: dual partition -> dinv -> CSR finalize
    k_init<<<1, 256, 0, stream>>>(scur, dcur);
    k_part<0><<<NE / TILE, 256, 0, stream>>>(src, dst, ew, scur, sbuck);
    k_part<1><<<NE / TILE, 256, 0, stream>>>(src, dst, ew, dcur, dbuck);
    k_deg2<<<NBUCK, 512, 0, stream>>>(scur, sbuck, dinv);
    k_fin<<<NBUCK, 512, 0, stream>>>(dcur, dbuck, edata, rowbeg, rowend);

    // layer 1: 64 -> 32
    k_dual_gemm<TT, HH><<<NN / 256, 256, 0, stream>>>(x, W1_0, W1_1, dinv, A, B);
    k_gather<HH><<<NN / 16, 256, 0, stream>>>(rowbeg, rowend, edata, B, A, b1, dinv, D);

    // layer 2: 32 -> 32
    k_dual_gemm<HH, HH><<<NN / 256, 256, 0, stream>>>(D, W2_0, W2_1, dinv, A, B);
    k_gather<HH><<<NN / 16, 256, 0, stream>>>(rowbeg, rowend, edata, B, A, b2, dinv, D);

    // layer 3: 32 -> 16
    k_dual_gemm<HH, BSC><<<NN / 256, 256, 0, stream>>>(D, W3_0, W3_1, dinv, A, B);
    k_gather<BSC><<<NN / 32, 256, 0, stream>>>(rowbeg, rowend, edata, B, A, b3, dinv, D); // h3 in D

    // collapsed FC head
    k_w23<<<(F1 * NC + 255) / 256, 256, 0, stream>>>(fc2w, fc3w, w23);
    k_bc<<<1, 64, 0, stream>>>(fc1b, fc2b, fc3b, fc3w, w23, bc);
    float* T1 = A;   // [6400,128]
    k_t1<<<FIN / 16, 256, 0, stream>>>(fc1w, fc2w, T1);
    float* Wc = B;   // [6400,9]
    k_wc<<<FIN * 16 / 256, 256, 0, stream>>>(T1, fc3w, Wc);
    k_out<<<NG, 256, 0, stream>>>(D, Wc, bc, out);
}